// Round 12
// baseline (196.619 us; speedup 1.0000x reference)
//
#include <hip/hip_runtime.h>
#include <stdint.h>
#include <math.h>

#define C_NUM 65536
#define NPT 24
#define NDRAW 524288u    // c*k*2 draws per uniform call

static __host__ __device__ __forceinline__ void tf2x32(uint32_t k0, uint32_t k1,
                                                       uint32_t& x0, uint32_t& x1) {
  const uint32_t ks2 = k0 ^ k1 ^ 0x1BD11BDAu;
#define TF_R(r) { x0 += x1; x1 = (x1 << (r)) | (x1 >> (32 - (r))); x1 ^= x0; }
  x0 += k0; x1 += k1;
  TF_R(13) TF_R(15) TF_R(26) TF_R(6)
  x0 += k1;  x1 += ks2 + 1u;
  TF_R(17) TF_R(29) TF_R(16) TF_R(24)
  x0 += ks2; x1 += k0 + 2u;
  TF_R(13) TF_R(15) TF_R(26) TF_R(6)
  x0 += k0;  x1 += k1 + 3u;
  TF_R(17) TF_R(29) TF_R(16) TF_R(24)
  x0 += k1;  x1 += ks2 + 4u;
  TF_R(13) TF_R(15) TF_R(26) TF_R(6)
  x0 += ks2; x1 += k0 + 5u;
#undef TF_R
}

// f64 uniform [0,1): bits64 = (out0<<32)|out1 of block (0, idx); u = (bits>>12)*2^-52
// (jax x64 partitionable uniform; validated R7: only draw variant that moved absmax)
__device__ __forceinline__ double jax_u01d(uint32_t ka, uint32_t kb, uint32_t idx) {
  uint32_t x0 = 0u, x1 = idx;
  tf2x32(ka, kb, x0, x1);
  const uint64_t bits = (((uint64_t)x0) << 32) | (uint64_t)x1;
  return (double)(bits >> 12) * 2.220446049250313e-16;  // 2^-52
}

// XLA:CPU llvm_ir_runtime GenerateVF32Exp, bitwise replica (FMA-contracted, as LLVM
// emits under XLA fast-math on an FMA-capable x86 host):
//   clamp x to [exp_lo, exp_hi] FIRST; fx = floor(fma(x, log2e, 0.5));
//   r = fma(fx,-C1,x); r = fma(fx, 2.12194440e-4, r)   [C2 = -2.12194440e-4]
//   plain Horner p0..p5; y = fma(y, r*r, r); y = y + 1.0f (separate add);
//   scale by 2^fx via exponent-bits multiply.
__device__ __forceinline__ float xla_vf32_exp(float x) {
  float xc = fminf(x, 88.3762626647950f);     // exp_hi
  xc = fmaxf(xc, -87.3365478515625f);         // exp_lo
  const float fx = floorf(fmaf(xc, 1.44269504088896341f, 0.5f));
  float r = fmaf(fx, -0.693359375f, xc);      // cephes_exp_C1
  r = fmaf(fx, 2.12194440e-4f, r);            // -C2
  const float z = __fmul_rn(r, r);
  float y = 1.9875691500e-4f;                 // p0
  y = fmaf(y, r, 1.3981999507e-3f);           // p1
  y = fmaf(y, r, 8.3334519073e-3f);           // p2
  y = fmaf(y, r, 4.1665795894e-2f);           // p3
  y = fmaf(y, r, 1.6666665459e-1f);           // p4
  y = fmaf(y, r, 5.0000001201e-1f);           // p5
  y = fmaf(y, z, r);
  y = __fadd_rn(y, 1.0f);
  const int n = (int)fx;                      // our inputs: |fx| <= ~9, exact scale
  return __fmul_rn(y, __uint_as_float((uint32_t)(127 + n) << 23));
}

// exp(-a) with underflow shortcut; a >= 0 (smooth path, f64)
static __device__ __forceinline__ double gexp(double a) {
  return (a > 700.0) ? 0.0 : exp(-a);
}

// ---------------- Kernel A: per-row cols + weights -> table ----------------
// means: f32 exp-form logistic with XLA GenerateVF32Exp; smooth parts f64.
__global__ void __launch_bounds__(256) wkern(const float* __restrict__ params,
                                             int* __restrict__ tab,
                                             uint32_t kr0, uint32_t kr1,
                                             uint32_t kg0, uint32_t kg1) {
  const int row = blockIdx.x * 256 + threadIdx.x;
  if (row >= C_NUM) return;

  const double c1 = 1.0 - 1e-6;  // (1.0 - EPSILON), f64

  float m32[4];
  double means[4], sigv[4], valv[4];
#pragma unroll
  for (int kk = 0; kk < 4; ++kk) {
    const int r = row * 4 + kk;
    const float p0 = params[r * 3 + 0];
    const double p1 = (double)params[r * 3 + 1];
    const double p2 = (double)params[r * 3 + 2];
    // XLA logistic (exp-form): s = 1/(1 + exp(-x)); means = s * 65535  (all f32)
    const float e32 = xla_vf32_exp(-p0);
    const float s32 = __fdiv_rn(1.0f, __fadd_rn(1.0f, e32));
    m32[kk] = __fmul_rn(s32, 65535.0f);
    means[kk] = (double)m32[kk];
    const double xx = p1 + 2.0;
    const double sp = fmax(xx, 0.0) + log1p(exp(-fabs(xx)));  // softplus smooth -> f64
    sigv[kk] = 1e-6 + ((sp + 1e-6) * 65536.0) * 0.2;          // EPSILON + sigma
    valv[kk] = p2;
  }

  int pts[NPT];
#pragma unroll
  for (int kk = 0; kk < 4; ++kk) {
    const float m = m32[kk];
    pts[kk * 6 + 0] = (int)floorf(m);     // f32 boundaries on the f32 ref mean
    pts[kk * 6 + 1] = (int)ceilf(m);
    const float mr = rintf(m);            // jnp.round: half-to-even, f32
    float lowf = __fadd_rn(mr, -64.0f);
    if (lowf < 0.0f) lowf = 0.0f;
    if (__fadd_rn(mr, 64.0f) > 65536.0f) lowf = 65536.0f - 128.0f;
    const double lower = (double)lowf;    // integer-valued f32: exact promote
    const uint32_t base = (uint32_t)(row * 4 + kk) * 2u;
#pragma unroll
    for (int r2 = 0; r2 < 2; ++r2) {
      const double u = jax_u01d(kr0, kr1, base + (uint32_t)r2);
      pts[kk * 6 + 2 + r2] = (int)floor((u * c1) * 128.0 + lower);  // f64; *128 exact
    }
#pragma unroll
    for (int r2 = 0; r2 < 2; ++r2) {
      const double u = jax_u01d(kg0, kg1, base + (uint32_t)r2);
      pts[kk * 6 + 4 + r2] = (int)floor((u * c1) * 65536.0);        // *65536 exact
    }
  }

  // dup[j] = exists j' < j with pts[j'] == pts[j] (stable argsort round-trip)
  uint32_t dup = 0u;
#pragma unroll
  for (int j = 1; j < NPT; ++j) {
    const int pj = pts[j];
    bool d = false;
#pragma unroll
    for (int j2 = 0; j2 < NPT - 1; ++j2) {
      if (j2 < j) d = d || (pts[j2] == pj);
    }
    if (d) dup |= (1u << j);
  }

  // pass 1: per-k normalization sums over non-dup points (f64, smooth)
  double S[4] = {0.0, 0.0, 0.0, 0.0};
#pragma unroll
  for (int j = 0; j < NPT; ++j) {
    if ((dup >> j) & 1u) continue;
#pragma unroll
    for (int kk = 0; kk < 4; ++kk) {
      const double d = (double)pts[j] - means[kk];
      S[kk] += gexp(0.5 * d * d / sigv[kk]);
    }
  }
  double t[4];
#pragma unroll
  for (int kk = 0; kk < 4; ++kk) t[kk] = valv[kk] / S[kk];

  // pass 2: weights, self-mask, emit (f32 store: 1e-7 rel << 2% threshold)
  int* cb = tab + (size_t)row * 48;
  float* wb = (float*)(cb + 24);
#pragma unroll
  for (int j = 0; j < NPT; ++j) {
    double w = 0.0;
    if (!((dup >> j) & 1u)) {
      double acc = 0.0;
#pragma unroll
      for (int kk = 0; kk < 4; ++kk) {
        const double d = (double)pts[j] - means[kk];
        acc += gexp(0.5 * d * d / sigv[kk]) * t[kk];
      }
      w = acc;
    }
    if (pts[j] == row) w = 0.0;  // rows == cols mask
    cb[j] = pts[j];
    wb[j] = (float)w;
  }
}

// ---------------- Kernel B: gather-weighted sum, f32 output ----------------
__global__ void __launch_bounds__(256) gkern(const float4* __restrict__ x4,
                                             const int* __restrict__ tab,
                                             float4* __restrict__ out4) {
  __shared__ int sws[8 * 48];
  const int tid = threadIdx.x;
  const int rb = blockIdx.x * 8;
  {
    const int* src = tab + (size_t)rb * 48;
#pragma unroll
    for (int t = tid; t < 8 * 48; t += 256) sws[t] = src[t];
  }
  __syncthreads();

  const int sub = tid >> 5;
  const int lane = tid & 31;
  const int* cb = sws + sub * 48;
  const float* wb = (const float*)(cb + 24);

  float4 acc = make_float4(0.f, 0.f, 0.f, 0.f);
#pragma unroll
  for (int j = 0; j < NPT; ++j) {
    const float w = wb[j];
    if (fabsf(w) > 1e-6f) {  // dups/self/underflowed carry (near-)zero weight
      const int c = cb[j];
      const float4 xv = x4[(size_t)c * 32 + lane];
      acc.x = fmaf(w, xv.x, acc.x);
      acc.y = fmaf(w, xv.y, acc.y);
      acc.z = fmaf(w, xv.z, acc.z);
      acc.w = fmaf(w, xv.w, acc.w);
    }
  }
  out4[(size_t)(rb + sub) * 32 + lane] = acc;
}

extern "C" void kernel_launch(void* const* d_in, const int* in_sizes, int n_in,
                              void* d_out, int out_size, void* d_ws, size_t ws_size,
                              hipStream_t stream) {
  const float* params = (const float*)d_in[0];
  const float* x = (const float*)d_in[1];
  if (n_in >= 2 && in_sizes[0] > in_sizes[1]) {  // order guard
    const float* tmp = params; params = x; x = tmp;
  }
  int* d_tab = (int*)d_ws;

  // split(jax.random.key(42)), partitionable/foldlike: key_i = block(key, (0, i))
  uint32_t kr0, kr1, kg0, kg1;
  { uint32_t a0 = 0u, a1 = 0u; tf2x32(0u, 42u, a0, a1); kr0 = a0; kr1 = a1; }
  { uint32_t b0 = 0u, b1 = 1u; tf2x32(0u, 42u, b0, b1); kg0 = b0; kg1 = b1; }

  hipLaunchKernelGGL(wkern, dim3(C_NUM / 256), dim3(256), 0, stream,
                     params, d_tab, kr0, kr1, kg0, kg1);
  hipLaunchKernelGGL(gkern, dim3(C_NUM / 8), dim3(256), 0, stream,
                     (const float4*)x, d_tab, (float4*)d_out);
}